// Round 1
// baseline (364.067 us; speedup 1.0000x reference)
//
#include <hip/hip_runtime.h>

// ---------------------------------------------------------------------------
// MultiHeadAttention: out = (softmax(split_heads(XqWq^T+bq) @ split_heads(XkWk^T+bk)^T / sqrt(64))
//                            @ split_heads(XvWv^T+bv)) merged @ Wo^T + bo
// B=2, S=2048, D_MODEL=1024, H=16, Dk=64.  All fp32 I/O; bf16 MFMA compute.
// ---------------------------------------------------------------------------

typedef short bf16x8 __attribute__((ext_vector_type(8)));
typedef float f32x4 __attribute__((ext_vector_type(4)));

#define D_MODEL 1024
#define NHEAD 16
#define DK 64
#define BB 2
#define SS 2048
#define MROWS (BB * SS) /* 4096 */

__device__ __forceinline__ unsigned short f2bf(float f) {
  unsigned u = __builtin_bit_cast(unsigned, f);
  u += 0x7fffu + ((u >> 16) & 1u);  // RNE
  return (unsigned short)(u >> 16);
}
__device__ __forceinline__ unsigned pack2(float a, float b) {
  return (unsigned)f2bf(a) | ((unsigned)f2bf(b) << 16);
}

// ---------------------------------------------------------------------------
// GEMM core: C[M=4096, N=1024] = A[4096,1024] * B[1024,1024]^T + bias
// A is fp32 (A_BF16=false) or bf16 (true). Output fp32 or bf16.
// 128x128 tile, BK=64, 4 waves (2x2), each wave 64x64 (4x4 fragments).
// LDS XOR-swizzled (group-of-8-bf16 ^ row&7) for conflict-free ds_read_b128.
// ---------------------------------------------------------------------------
template <bool A_BF16, bool OUT_BF16>
__device__ __forceinline__ void gemm_core(const float* __restrict__ Af,
                                          const unsigned short* __restrict__ Ab,
                                          const float* __restrict__ B,
                                          const float* __restrict__ bias,
                                          float* __restrict__ Cf,
                                          unsigned short* __restrict__ Cb) {
  const int K = D_MODEL, N = D_MODEL;
  __shared__ __align__(16) unsigned short As[128 * 64];
  __shared__ __align__(16) unsigned short Bs[128 * 64];
  const int tid = threadIdx.x;
  const int lane = tid & 63, w = tid >> 6;
  const int wm = w >> 1, wn = w & 1;
  const int l15 = lane & 15, l4 = lane >> 4;
  const int bm = blockIdx.y, bn = blockIdx.x;

  f32x4 acc[4][4];
#pragma unroll
  for (int m = 0; m < 4; ++m)
#pragma unroll
    for (int n = 0; n < 4; ++n) acc[m][n] = (f32x4){0.f, 0.f, 0.f, 0.f};

  for (int k0 = 0; k0 < K; k0 += 64) {
    __syncthreads();
#pragma unroll
    for (int it = 0; it < 4; ++it) {
      const int flat = it * 256 + tid;      // 0..1023
      const int row = flat >> 3, g = flat & 7;
      const int dst = row * 64 + ((g ^ (row & 7)) << 3);
      if (A_BF16) {
        uint4 va = *(const uint4*)&Ab[(size_t)(bm * 128 + row) * K + k0 + g * 8];
        *(uint4*)&As[dst] = va;
      } else {
        const float* src = &Af[(size_t)(bm * 128 + row) * K + k0 + g * 8];
        float4 v0 = *(const float4*)src;
        float4 v1 = *(const float4*)(src + 4);
        uint4 p;
        p.x = pack2(v0.x, v0.y); p.y = pack2(v0.z, v0.w);
        p.z = pack2(v1.x, v1.y); p.w = pack2(v1.z, v1.w);
        *(uint4*)&As[dst] = p;
      }
      {
        const float* src = &B[(size_t)(bn * 128 + row) * K + k0 + g * 8];
        float4 v0 = *(const float4*)src;
        float4 v1 = *(const float4*)(src + 4);
        uint4 p;
        p.x = pack2(v0.x, v0.y); p.y = pack2(v0.z, v0.w);
        p.z = pack2(v1.x, v1.y); p.w = pack2(v1.z, v1.w);
        *(uint4*)&Bs[dst] = p;
      }
    }
    __syncthreads();
#pragma unroll
    for (int kk = 0; kk < 2; ++kk) {
      bf16x8 afr[4], bfr[4];
#pragma unroll
      for (int m = 0; m < 4; ++m) {
        const int r = wm * 64 + m * 16 + l15;
        afr[m] = *(const bf16x8*)&As[r * 64 + (((kk * 4 + l4) ^ (r & 7)) << 3)];
      }
#pragma unroll
      for (int n = 0; n < 4; ++n) {
        const int r = wn * 64 + n * 16 + l15;
        bfr[n] = *(const bf16x8*)&Bs[r * 64 + (((kk * 4 + l4) ^ (r & 7)) << 3)];
      }
#pragma unroll
      for (int m = 0; m < 4; ++m)
#pragma unroll
        for (int n = 0; n < 4; ++n)
          acc[m][n] = __builtin_amdgcn_mfma_f32_16x16x32_bf16(afr[m], bfr[n], acc[m][n], 0, 0, 0);
    }
  }
#pragma unroll
  for (int m = 0; m < 4; ++m)
#pragma unroll
    for (int n = 0; n < 4; ++n) {
      const int col = bn * 128 + wn * 64 + n * 16 + l15;
      const float bv = bias[col];
#pragma unroll
      for (int r = 0; r < 4; ++r) {
        const int row = bm * 128 + wm * 64 + m * 16 + l4 * 4 + r;
        const float v = acc[m][n][r] + bv;
        if (OUT_BF16) Cb[(size_t)row * N + col] = f2bf(v);
        else          Cf[(size_t)row * N + col] = v;
      }
    }
}

// Fused Q/K/V projections: blockIdx.z selects which projection -> 768 blocks.
__global__ __launch_bounds__(256) void gemm_qkv(
    const float* __restrict__ Q, const float* __restrict__ K, const float* __restrict__ V,
    const float* __restrict__ Wq, const float* __restrict__ bq,
    const float* __restrict__ Wk, const float* __restrict__ bk,
    const float* __restrict__ Wv, const float* __restrict__ bv,
    unsigned short* __restrict__ q, unsigned short* __restrict__ k,
    unsigned short* __restrict__ v) {
  const int z = blockIdx.z;
  const float* X = (z == 0) ? Q : (z == 1) ? K : V;
  const float* W = (z == 0) ? Wq : (z == 1) ? Wk : Wv;
  const float* bi = (z == 0) ? bq : (z == 1) ? bk : bv;
  unsigned short* O = (z == 0) ? q : (z == 1) ? k : v;
  gemm_core<false, true>(X, nullptr, W, bi, nullptr, O);
}

__global__ __launch_bounds__(256) void gemm_o(const unsigned short* __restrict__ A,
                                              const float* __restrict__ W,
                                              const float* __restrict__ bi,
                                              float* __restrict__ out) {
  gemm_core<true, false>(nullptr, A, W, bi, out, nullptr);
}

// ---------------------------------------------------------------------------
// Flash attention: block = (b, h, 128 q-rows), 4 waves x 32 q-rows each.
// K-tile loop of 64 keys: stage K[64][64] and V^T[64][64] (bf16, swizzled LDS),
// QK^T via MFMA, online softmax in 16-lane row groups, P->LDS->A-frag, PV MFMA.
// ---------------------------------------------------------------------------
__global__ __launch_bounds__(256) void attn_kernel(
    const unsigned short* __restrict__ Qp, const unsigned short* __restrict__ Kp,
    const unsigned short* __restrict__ Vp, unsigned short* __restrict__ Op) {
  __shared__ __align__(16) unsigned short Kt[64 * 64];
  __shared__ __align__(16) unsigned short Vt[64 * 64];     // transposed: [d][s]
  __shared__ __align__(16) unsigned short Pl[4][32 * 64];  // per-wave P tile
  const int tid = threadIdx.x;
  const int lane = tid & 63, w = tid >> 6;
  const int l15 = lane & 15, l4 = lane >> 4;
  const int bh = blockIdx.x;           // 0..31
  const int b = bh >> 4, h = bh & 15;
  const int qb = blockIdx.y;           // 0..15
  const size_t base = (size_t)b * SS * D_MODEL + (size_t)h * DK;
  const float c1 = 0.18033688011112042f;  // (1/8) * log2(e)

  // Q fragments held in registers for the whole K loop.
  bf16x8 aq[2][2];
#pragma unroll
  for (int m = 0; m < 2; ++m) {
    const int qrow = qb * 128 + w * 32 + m * 16 + l15;
#pragma unroll
    for (int kk = 0; kk < 2; ++kk)
      aq[m][kk] = *(const bf16x8*)&Qp[base + (size_t)qrow * D_MODEL + kk * 32 + l4 * 8];
  }

  float rm[2][4], rs[2][4];
  f32x4 acc_o[2][4];
#pragma unroll
  for (int m = 0; m < 2; ++m)
#pragma unroll
    for (int r = 0; r < 4; ++r) { rm[m][r] = -1e30f; rs[m][r] = 0.f; }
#pragma unroll
  for (int m = 0; m < 2; ++m)
#pragma unroll
    for (int d = 0; d < 4; ++d) acc_o[m][d] = (f32x4){0.f, 0.f, 0.f, 0.f};

  for (int kt = 0; kt < SS / 64; ++kt) {
    __syncthreads();
    // stage K tile: rows=key, cols=d, swizzled
#pragma unroll
    for (int it = 0; it < 2; ++it) {
      const int flat = it * 256 + tid;  // 0..511
      const int s = flat >> 3, g = flat & 7;
      *(uint4*)&Kt[s * 64 + ((g ^ (s & 7)) << 3)] =
          *(const uint4*)&Kp[base + (size_t)(kt * 64 + s) * D_MODEL + g * 8];
    }
    // stage V tile transposed: Vt[d][s]
#pragma unroll
    for (int it = 0; it < 4; ++it) {
      const int flat = it * 256 + tid;  // 0..1023
      const int s = flat & 63, d0 = (flat >> 6) * 4;
      uint2 vv = *(const uint2*)&Vp[base + (size_t)(kt * 64 + s) * D_MODEL + d0];
      const unsigned short e0 = vv.x & 0xffff, e1 = vv.x >> 16;
      const unsigned short e2 = vv.y & 0xffff, e3 = vv.y >> 16;
      Vt[(d0 + 0) * 64 + (((s >> 3) ^ ((d0 + 0) & 7)) << 3) + (s & 7)] = e0;
      Vt[(d0 + 1) * 64 + (((s >> 3) ^ ((d0 + 1) & 7)) << 3) + (s & 7)] = e1;
      Vt[(d0 + 2) * 64 + (((s >> 3) ^ ((d0 + 2) & 7)) << 3) + (s & 7)] = e2;
      Vt[(d0 + 3) * 64 + (((s >> 3) ^ ((d0 + 3) & 7)) << 3) + (s & 7)] = e3;
    }
    __syncthreads();

    // scores: 32 q-rows x 64 keys per wave
    f32x4 sc[2][4];
#pragma unroll
    for (int m = 0; m < 2; ++m)
#pragma unroll
      for (int n = 0; n < 4; ++n) sc[m][n] = (f32x4){0.f, 0.f, 0.f, 0.f};
#pragma unroll
    for (int kk = 0; kk < 2; ++kk) {
      bf16x8 bk[4];
#pragma unroll
      for (int n = 0; n < 4; ++n) {
        const int r = n * 16 + l15;
        bk[n] = *(const bf16x8*)&Kt[r * 64 + (((kk * 4 + l4) ^ (r & 7)) << 3)];
      }
#pragma unroll
      for (int m = 0; m < 2; ++m)
#pragma unroll
        for (int n = 0; n < 4; ++n)
          sc[m][n] = __builtin_amdgcn_mfma_f32_16x16x32_bf16(aq[m][kk], bk[n], sc[m][n], 0, 0, 0);
    }

    // online softmax per row (rows live in 16-lane groups)
#pragma unroll
    for (int m = 0; m < 2; ++m) {
#pragma unroll
      for (int r = 0; r < 4; ++r) {
        float mx = fmaxf(fmaxf(sc[m][0][r], sc[m][1][r]), fmaxf(sc[m][2][r], sc[m][3][r]));
#pragma unroll
        for (int t = 1; t < 16; t <<= 1) mx = fmaxf(mx, __shfl_xor(mx, t));
        const float nm = fmaxf(rm[m][r], mx);
        const float alpha = exp2f((rm[m][r] - nm) * c1);
        rm[m][r] = nm;
        float ps = 0.f;
#pragma unroll
        for (int n = 0; n < 4; ++n) {
          const float p = exp2f((sc[m][n][r] - nm) * c1);
          sc[m][n][r] = p;
          ps += p;
        }
#pragma unroll
        for (int t = 1; t < 16; t <<= 1) ps += __shfl_xor(ps, t);
        rs[m][r] = rs[m][r] * alpha + ps;
#pragma unroll
        for (int d = 0; d < 4; ++d) acc_o[m][d][r] *= alpha;
      }
    }

    // write P (bf16) to per-wave LDS in A-fragment-friendly swizzled layout
#pragma unroll
    for (int m = 0; m < 2; ++m)
#pragma unroll
      for (int n = 0; n < 4; ++n)
#pragma unroll
        for (int r = 0; r < 4; ++r) {
          const int row = m * 16 + l4 * 4 + r;
          const int col = n * 16 + l15;
          Pl[w][row * 64 + (((col >> 3) ^ (row & 7)) << 3) + (col & 7)] = f2bf(sc[m][n][r]);
        }
    __syncthreads();

    // PV
#pragma unroll
    for (int kk = 0; kk < 2; ++kk) {
      bf16x8 ap[2], bv[4];
#pragma unroll
      for (int m = 0; m < 2; ++m) {
        const int r = m * 16 + l15;
        ap[m] = *(const bf16x8*)&Pl[w][r * 64 + (((kk * 4 + l4) ^ (r & 7)) << 3)];
      }
#pragma unroll
      for (int d = 0; d < 4; ++d) {
        const int r = d * 16 + l15;
        bv[d] = *(const bf16x8*)&Vt[r * 64 + (((kk * 4 + l4) ^ (r & 7)) << 3)];
      }
#pragma unroll
      for (int m = 0; m < 2; ++m)
#pragma unroll
        for (int d = 0; d < 4; ++d)
          acc_o[m][d] = __builtin_amdgcn_mfma_f32_16x16x32_bf16(ap[m], bv[d], acc_o[m][d], 0, 0, 0);
    }
  }

  // epilogue: normalize and store merged-head layout [B*S, D_MODEL] (bf16)
#pragma unroll
  for (int m = 0; m < 2; ++m)
#pragma unroll
    for (int d = 0; d < 4; ++d)
#pragma unroll
      for (int r = 0; r < 4; ++r) {
        const int qrow = qb * 128 + w * 32 + m * 16 + l4 * 4 + r;
        const float v = acc_o[m][d][r] / rs[m][r];
        Op[base + (size_t)qrow * D_MODEL + d * 16 + l15] = f2bf(v);
      }
}

extern "C" void kernel_launch(void* const* d_in, const int* in_sizes, int n_in,
                              void* d_out, int out_size, void* d_ws, size_t ws_size,
                              hipStream_t stream) {
  const float* Qin = (const float*)d_in[0];
  const float* Kin = (const float*)d_in[1];
  const float* Vin = (const float*)d_in[2];
  const float* Wq = (const float*)d_in[3];
  const float* bq = (const float*)d_in[4];
  const float* Wk = (const float*)d_in[5];
  const float* bk = (const float*)d_in[6];
  const float* Wv = (const float*)d_in[7];
  const float* bv = (const float*)d_in[8];
  const float* Wo = (const float*)d_in[9];
  const float* bo = (const float*)d_in[10];
  float* out = (float*)d_out;

  unsigned short* q = (unsigned short*)d_ws;
  unsigned short* k = q + (size_t)MROWS * D_MODEL;
  unsigned short* v = k + (size_t)MROWS * D_MODEL;
  unsigned short* ao = v + (size_t)MROWS * D_MODEL;  // total 32 MB of ws

  dim3 gqkv(D_MODEL / 128, MROWS / 128, 3);  // 8 x 32 x 3 = 768 blocks
  gemm_qkv<<<gqkv, 256, 0, stream>>>(Qin, Kin, Vin, Wq, bq, Wk, bk, Wv, bv, q, k, v);
  attn_kernel<<<dim3(BB * NHEAD, SS / 128), 256, 0, stream>>>(q, k, v, ao);
  gemm_o<<<dim3(D_MODEL / 128, MROWS / 128), 256, 0, stream>>>(ao, Wo, bo, out);
}

// Round 2
// 318.006 us; speedup vs baseline: 1.1448x; 1.1448x over previous
//
#include <hip/hip_runtime.h>

// ---------------------------------------------------------------------------
// MHA: out = (softmax(split(XqWq^T+bq) @ split(XkWk^T+bk)^T / 8) @ split(XvWv^T+bv)) @ Wo^T + bo
// B=2, S=2048, D=1024, H=16, Dk=64. fp32 I/O; bf16 MFMA compute.
// R2: bf16-convert pass + global_load_lds GEMMs + swapped-QK^T in-reg-softmax attention.
// ---------------------------------------------------------------------------

typedef short bf16x8 __attribute__((ext_vector_type(8)));
typedef float f32x4 __attribute__((ext_vector_type(4)));

#define D_MODEL 1024
#define NHEAD 16
#define DK 64
#define BB 2
#define SS 2048
#define MROWS (BB * SS) /* 4096 */

__device__ __forceinline__ unsigned short f2bf(float f) {
  unsigned u = __builtin_bit_cast(unsigned, f);
  u += 0x7fffu + ((u >> 16) & 1u);  // RNE
  return (unsigned short)(u >> 16);
}
__device__ __forceinline__ unsigned pack2(float a, float b) {
  return (unsigned)f2bf(a) | ((unsigned)f2bf(b) << 16);
}

typedef __attribute__((address_space(3))) unsigned int as3u;
typedef const __attribute__((address_space(1))) unsigned int as1u;
// Async global->LDS, 16B/lane. LDS dest is wave-uniform base + lane*16.
__device__ __forceinline__ void gload16(void* lds, const void* g) {
  __builtin_amdgcn_global_load_lds((as1u*)g, (as3u*)lds, 16, 0, 0);
}

// ---------------------------------------------------------------------------
// fp32 -> bf16 conversion pass (memory-bound, ~100 MB traffic ≈ 15 us)
// ---------------------------------------------------------------------------
struct CvtArgs {
  const float* s[7];
  unsigned short* d[7];
  int n8[7];
};

__global__ __launch_bounds__(256) void convert_bf16(CvtArgs a) {
  const int slot = blockIdx.y;
  const float* __restrict__ s = a.s[slot];
  unsigned short* __restrict__ d = a.d[slot];
  const int n8 = a.n8[slot];
  for (int i = blockIdx.x * 256 + threadIdx.x; i < n8; i += gridDim.x * 256) {
    const size_t off = (size_t)i * 8;
    const float4 v0 = *(const float4*)&s[off];
    const float4 v1 = *(const float4*)&s[off + 4];
    uint4 p;
    p.x = pack2(v0.x, v0.y); p.y = pack2(v0.z, v0.w);
    p.z = pack2(v1.x, v1.y); p.w = pack2(v1.z, v1.w);
    *(uint4*)&d[off] = p;
  }
}

// ---------------------------------------------------------------------------
// bf16 GEMM: C[4096,1024] = A[4096,1024] * B[1024,1024]^T + bias
// 128x128 tile, BK=64, 4 waves (2x2). global_load_lds w=16 staging with
// pre-swizzled source (LDS linear, content XOR-swizzled for ds_read_b128).
// ---------------------------------------------------------------------------
template <bool OUT_BF16>
__device__ __forceinline__ void gemm_bf16_core(const unsigned short* __restrict__ A,
                                               const unsigned short* __restrict__ B,
                                               const float* __restrict__ bias,
                                               float* __restrict__ Cf,
                                               unsigned short* __restrict__ Cb) {
  __shared__ __align__(16) unsigned short As[128 * 64];
  __shared__ __align__(16) unsigned short Bs[128 * 64];
  const int tid = threadIdx.x;
  const int lane = tid & 63, w = tid >> 6;
  const int wm = w >> 1, wn = w & 1;
  const int l15 = lane & 15, l4 = lane >> 4;
  const int bm = blockIdx.y, bn = blockIdx.x;

  f32x4 acc[4][4];
#pragma unroll
  for (int m = 0; m < 4; ++m)
#pragma unroll
    for (int n = 0; n < 4; ++n) acc[m][n] = (f32x4){0.f, 0.f, 0.f, 0.f};

  for (int k0 = 0; k0 < D_MODEL; k0 += 64) {
    __syncthreads();
#pragma unroll
    for (int i = 0; i < 4; ++i) {
      const int flat = (w * 4 + i) * 64 + lane;
      const int row = flat >> 3, g = flat & 7;
      const int gs = (g ^ (row & 7)) * 8;  // pre-swizzled source column group
      gload16(&As[flat * 8], &A[(size_t)(bm * 128 + row) * D_MODEL + k0 + gs]);
      gload16(&Bs[flat * 8], &B[(size_t)(bn * 128 + row) * D_MODEL + k0 + gs]);
    }
    __syncthreads();
#pragma unroll
    for (int kk = 0; kk < 2; ++kk) {
      bf16x8 af[4], bf[4];
#pragma unroll
      for (int m = 0; m < 4; ++m) {
        const int r = wm * 64 + m * 16 + l15;
        af[m] = *(const bf16x8*)&As[r * 64 + (((kk * 4 + l4) ^ (r & 7)) << 3)];
      }
#pragma unroll
      for (int n = 0; n < 4; ++n) {
        const int r = wn * 64 + n * 16 + l15;
        bf[n] = *(const bf16x8*)&Bs[r * 64 + (((kk * 4 + l4) ^ (r & 7)) << 3)];
      }
#pragma unroll
      for (int m = 0; m < 4; ++m)
#pragma unroll
        for (int n = 0; n < 4; ++n)
          acc[m][n] = __builtin_amdgcn_mfma_f32_16x16x32_bf16(af[m], bf[n], acc[m][n], 0, 0, 0);
    }
  }
#pragma unroll
  for (int m = 0; m < 4; ++m)
#pragma unroll
    for (int n = 0; n < 4; ++n) {
      const int col = bn * 128 + wn * 64 + n * 16 + l15;
      const float bv = bias[col];
#pragma unroll
      for (int r = 0; r < 4; ++r) {
        const int row = bm * 128 + wm * 64 + m * 16 + l4 * 4 + r;
        const float v = acc[m][n][r] + bv;
        if (OUT_BF16) Cb[(size_t)row * D_MODEL + col] = f2bf(v);
        else          Cf[(size_t)row * D_MODEL + col] = v;
      }
    }
}

__global__ __launch_bounds__(256) void gemm_qkv(
    const unsigned short* __restrict__ Xq, const unsigned short* __restrict__ Xk,
    const unsigned short* __restrict__ Xv,
    const unsigned short* __restrict__ Wq, const float* __restrict__ bq,
    const unsigned short* __restrict__ Wk, const float* __restrict__ bk,
    const unsigned short* __restrict__ Wv, const float* __restrict__ bv,
    unsigned short* __restrict__ q, unsigned short* __restrict__ k,
    unsigned short* __restrict__ v) {
  const int z = blockIdx.z;
  const unsigned short* X = (z == 0) ? Xq : (z == 1) ? Xk : Xv;
  const unsigned short* W = (z == 0) ? Wq : (z == 1) ? Wk : Wv;
  const float* bi = (z == 0) ? bq : (z == 1) ? bk : bv;
  unsigned short* O = (z == 0) ? q : (z == 1) ? k : v;
  gemm_bf16_core<true>(X, W, bi, nullptr, O);
}

__global__ __launch_bounds__(256) void gemm_o(const unsigned short* __restrict__ A,
                                              const unsigned short* __restrict__ W,
                                              const float* __restrict__ bi,
                                              float* __restrict__ out) {
  gemm_bf16_core<false>(A, W, bi, out, nullptr);
}

// ---------------------------------------------------------------------------
// Flash attention, swapped-QK^T form. Block = (b,h, 64 q-rows), 4 waves x 16
// q-rows. Per KV-tile(64): stage K (gload_lds, pre-swizzled) + V^T (reg path),
// ST = mfma(K,Q) so lane l15 owns one q-row's scores -> in-reg softmax with
// only 2 shfl rounds; P packed to per-wave LDS (u32 writes, no barrier); PV.
// ---------------------------------------------------------------------------
__global__ __launch_bounds__(256) void attn_kernel(
    const unsigned short* __restrict__ Qp, const unsigned short* __restrict__ Kp,
    const unsigned short* __restrict__ Vp, unsigned short* __restrict__ Op) {
  __shared__ __align__(16) unsigned short Kt[64 * 64];
  __shared__ __align__(16) unsigned short Vt[64 * 64];     // [d][s] transposed
  __shared__ __align__(16) unsigned short Pt[4][16 * 64];  // per-wave P
  const int tid = threadIdx.x;
  const int lane = tid & 63, w = tid >> 6;
  const int l15 = lane & 15, l4 = lane >> 4;
  const int bh = blockIdx.x;  // 0..31
  const int b = bh >> 4, h = bh & 15;
  const int qb = blockIdx.y;  // 0..31 (64 rows each)
  const size_t base = (size_t)b * SS * D_MODEL + (size_t)h * DK;
  const float c1 = 0.18033688011112042f;  // (1/8)*log2(e)

  const int qrow = qb * 64 + w * 16 + l15;
  bf16x8 aq[2];
#pragma unroll
  for (int kk = 0; kk < 2; ++kk)
    aq[kk] = *(const bf16x8*)&Qp[base + (size_t)qrow * D_MODEL + kk * 32 + l4 * 8];

  float rm = -1e30f, rs = 0.f;
  f32x4 acc[4];
#pragma unroll
  for (int d = 0; d < 4; ++d) acc[d] = (f32x4){0.f, 0.f, 0.f, 0.f};

  for (int kt = 0; kt < SS / 64; ++kt) {
    __syncthreads();
    // K tile via global_load_lds (pre-swizzled source, linear LDS dest)
#pragma unroll
    for (int i = 0; i < 2; ++i) {
      const int flat = (w * 2 + i) * 64 + lane;
      const int row = flat >> 3, g = flat & 7;
      const int gs = (g ^ (row & 7)) * 8;
      gload16(&Kt[flat * 8], &Kp[base + (size_t)(kt * 64 + row) * D_MODEL + gs]);
    }
    // V tile transposed: coalesced 8B reads (16 lanes cover a 128B row)
#pragma unroll
    for (int i = 0; i < 4; ++i) {
      const int flat = i * 256 + tid;
      const int s = flat >> 4, d0 = (flat & 15) * 4;
      const uint2 vv = *(const uint2*)&Vp[base + (size_t)(kt * 64 + s) * D_MODEL + d0];
      const int sg = s >> 3, so = s & 7;
      Vt[(d0 + 0) * 64 + ((sg ^ ((d0 + 0) & 7)) << 3) + so] = (unsigned short)(vv.x & 0xffff);
      Vt[(d0 + 1) * 64 + ((sg ^ ((d0 + 1) & 7)) << 3) + so] = (unsigned short)(vv.x >> 16);
      Vt[(d0 + 2) * 64 + ((sg ^ ((d0 + 2) & 7)) << 3) + so] = (unsigned short)(vv.y & 0xffff);
      Vt[(d0 + 3) * 64 + ((sg ^ ((d0 + 3) & 7)) << 3) + so] = (unsigned short)(vv.y >> 16);
    }
    __syncthreads();

    // swapped QK^T: st[n] holds keys n*16+l4*4+r for q-row l15
    f32x4 st[4];
#pragma unroll
    for (int n = 0; n < 4; ++n) st[n] = (f32x4){0.f, 0.f, 0.f, 0.f};
#pragma unroll
    for (int kk = 0; kk < 2; ++kk) {
      bf16x8 kf[4];
#pragma unroll
      for (int n = 0; n < 4; ++n) {
        const int r = n * 16 + l15;
        kf[n] = *(const bf16x8*)&Kt[r * 64 + (((kk * 4 + l4) ^ (r & 7)) << 3)];
      }
#pragma unroll
      for (int n = 0; n < 4; ++n)
        st[n] = __builtin_amdgcn_mfma_f32_16x16x32_bf16(kf[n], aq[kk], st[n], 0, 0, 0);
    }

    // in-register online softmax (row = q = l15)
    float mx = st[0][0];
#pragma unroll
    for (int n = 0; n < 4; ++n)
#pragma unroll
      for (int r = 0; r < 4; ++r) mx = fmaxf(mx, st[n][r]);
    mx = fmaxf(mx, __shfl_xor(mx, 16));
    mx = fmaxf(mx, __shfl_xor(mx, 32));
    const bool grow = __any(mx > rm);
    if (grow) {  // exact: only rescale when the running max actually grows
      const float nm = fmaxf(rm, mx);
      const float alpha = exp2f((rm - nm) * c1);
      rm = nm;
      rs *= alpha;
#pragma unroll
      for (int r = 0; r < 4; ++r) {
        const float ar = __shfl(alpha, l4 * 4 + r);  // q of acc reg r
#pragma unroll
        for (int d = 0; d < 4; ++d) acc[d][r] *= ar;
      }
    }
    float ps = 0.f;
#pragma unroll
    for (int n = 0; n < 4; ++n)
#pragma unroll
      for (int r = 0; r < 4; ++r) {
        const float p = exp2f((st[n][r] - rm) * c1);
        st[n][r] = p;
        ps += p;
      }
    ps += __shfl_xor(ps, 16);
    ps += __shfl_xor(ps, 32);
    rs += ps;

    // P -> per-wave LDS (u32 pair writes, swizzled; no barrier needed)
#pragma unroll
    for (int n = 0; n < 4; ++n)
#pragma unroll
      for (int c = 0; c < 2; ++c) {
        const int col = n * 16 + l4 * 4 + 2 * c;
        const int sw = (((col >> 3) ^ (l15 & 7)) << 3) + (col & 7);
        *(unsigned*)&Pt[w][l15 * 64 + sw] = pack2(st[n][2 * c], st[n][2 * c + 1]);
      }

    // PV: acc[d] += P(A) * V(B)
#pragma unroll
    for (int kk = 0; kk < 2; ++kk) {
      const bf16x8 ap = *(const bf16x8*)&Pt[w][l15 * 64 + (((kk * 4 + l4) ^ (l15 & 7)) << 3)];
      bf16x8 vf[4];
#pragma unroll
      for (int d = 0; d < 4; ++d) {
        const int r = d * 16 + l15;
        vf[d] = *(const bf16x8*)&Vt[r * 64 + (((kk * 4 + l4) ^ (r & 7)) << 3)];
      }
#pragma unroll
      for (int d = 0; d < 4; ++d)
        acc[d] = __builtin_amdgcn_mfma_f32_16x16x32_bf16(ap, vf[d], acc[d], 0, 0, 0);
    }
  }

  // epilogue: acc rows are q = l4*4+r; fetch rs from lane l4*4+r
  float rsb[4];
#pragma unroll
  for (int r = 0; r < 4; ++r) rsb[r] = __shfl(rs, l4 * 4 + r);
#pragma unroll
  for (int d = 0; d < 4; ++d)
#pragma unroll
    for (int r = 0; r < 4; ++r) {
      const int orow = qb * 64 + w * 16 + l4 * 4 + r;
      Op[base + (size_t)orow * D_MODEL + d * 16 + l15] = f2bf(acc[d][r] / rsb[r]);
    }
}

extern "C" void kernel_launch(void* const* d_in, const int* in_sizes, int n_in,
                              void* d_out, int out_size, void* d_ws, size_t ws_size,
                              hipStream_t stream) {
  const float* Qin = (const float*)d_in[0];
  const float* Kin = (const float*)d_in[1];
  const float* Vin = (const float*)d_in[2];
  const float* Wq = (const float*)d_in[3];
  const float* bq = (const float*)d_in[4];
  const float* Wk = (const float*)d_in[5];
  const float* bk = (const float*)d_in[6];
  const float* Wv = (const float*)d_in[7];
  const float* bv = (const float*)d_in[8];
  const float* Wo = (const float*)d_in[9];
  const float* bo = (const float*)d_in[10];
  float* out = (float*)d_out;

  const size_t NX = (size_t)MROWS * D_MODEL;  // 4 Mi elems
  const size_t NW = (size_t)D_MODEL * D_MODEL;
  unsigned short* ws = (unsigned short*)d_ws;
  unsigned short* q  = ws;             // projected q (bf16)
  unsigned short* k  = ws + NX;        // projected k
  unsigned short* v  = ws + 2 * NX;    // projected v
  unsigned short* Xq = ws + 3 * NX;    // input Q bf16 (reused as ao after qkv)
  unsigned short* Xk = ws + 4 * NX;
  unsigned short* Xv = ws + 5 * NX;
  unsigned short* wq = ws + 6 * NX;
  unsigned short* wk = wq + NW;
  unsigned short* wv = wk + NW;
  unsigned short* wo = wv + NW;        // total 56 MB
  unsigned short* ao = Xq;             // alias: Xq dead after gemm_qkv

  CvtArgs ca;
  ca.s[0] = Qin; ca.d[0] = Xq; ca.n8[0] = (int)(NX / 8);
  ca.s[1] = Kin; ca.d[1] = Xk; ca.n8[1] = (int)(NX / 8);
  ca.s[2] = Vin; ca.d[2] = Xv; ca.n8[2] = (int)(NX / 8);
  ca.s[3] = Wq;  ca.d[3] = wq; ca.n8[3] = (int)(NW / 8);
  ca.s[4] = Wk;  ca.d[4] = wk; ca.n8[4] = (int)(NW / 8);
  ca.s[5] = Wv;  ca.d[5] = wv; ca.n8[5] = (int)(NW / 8);
  ca.s[6] = Wo;  ca.d[6] = wo; ca.n8[6] = (int)(NW / 8);
  convert_bf16<<<dim3(1024, 7), 256, 0, stream>>>(ca);

  gemm_qkv<<<dim3(D_MODEL / 128, MROWS / 128, 3), 256, 0, stream>>>(
      Xq, Xk, Xv, wq, bq, wk, bk, wv, bv, q, k, v);
  attn_kernel<<<dim3(BB * NHEAD, SS / 64), 256, 0, stream>>>(q, k, v, ao);
  gemm_o<<<dim3(D_MODEL / 128, MROWS / 128), 256, 0, stream>>>(ao, wo, bo, out);
}

// Round 3
// 252.424 us; speedup vs baseline: 1.4423x; 1.2598x over previous
//
#include <hip/hip_runtime.h>

// ---------------------------------------------------------------------------
// MHA: out = (softmax(split(XqWq^T+bq) @ split(XkWk^T+bk)^T / 8) @ split(XvWv^T+bv)) @ Wo^T + bo
// B=2, S=2048, D=1024, H=16, Dk=64. fp32 I/O; bf16 MFMA compute.
// R3: vT produced in gemm epilogue; attn stages K/V^T via global_load_lds only;
//     scale folded into q; BM=64 GEMM tiles for occupancy.
// ---------------------------------------------------------------------------

typedef short bf16x8 __attribute__((ext_vector_type(8)));
typedef float f32x4 __attribute__((ext_vector_type(4)));

#define D_MODEL 1024
#define NHEAD 16
#define DK 64
#define BB 2
#define SS 2048
#define MROWS (BB * SS) /* 4096 */
#define C1 0.18033688011112042f /* (1/8)*log2(e) */

__device__ __forceinline__ unsigned short f2bf(float f) {
  unsigned u = __builtin_bit_cast(unsigned, f);
  u += 0x7fffu + ((u >> 16) & 1u);  // RNE
  return (unsigned short)(u >> 16);
}
__device__ __forceinline__ unsigned pack2(float a, float b) {
  return (unsigned)f2bf(a) | ((unsigned)f2bf(b) << 16);
}
__device__ __forceinline__ unsigned cvtpk(float lo, float hi) {
  unsigned r;
  asm("v_cvt_pk_bf16_f32 %0, %1, %2" : "=v"(r) : "v"(lo), "v"(hi));
  return r;
}

typedef __attribute__((address_space(3))) unsigned int as3u;
typedef const __attribute__((address_space(1))) unsigned int as1u;
__device__ __forceinline__ void gload16(void* lds, const void* g) {
  __builtin_amdgcn_global_load_lds((as1u*)g, (as3u*)lds, 16, 0, 0);
}

// ---------------------------------------------------------------------------
// fp32 -> bf16 conversion pass
// ---------------------------------------------------------------------------
struct CvtArgs {
  const float* s[7];
  unsigned short* d[7];
  int n8[7];
};

__global__ __launch_bounds__(256) void convert_bf16(CvtArgs a) {
  const int slot = blockIdx.y;
  const float* __restrict__ s = a.s[slot];
  unsigned short* __restrict__ d = a.d[slot];
  const int n8 = a.n8[slot];
  for (int i = blockIdx.x * 256 + threadIdx.x; i < n8; i += gridDim.x * 256) {
    const size_t off = (size_t)i * 8;
    const float4 v0 = *(const float4*)&s[off];
    const float4 v1 = *(const float4*)&s[off + 4];
    uint4 p;
    p.x = pack2(v0.x, v0.y); p.y = pack2(v0.z, v0.w);
    p.z = pack2(v1.x, v1.y); p.w = pack2(v1.z, v1.w);
    *(uint4*)&d[off] = p;
  }
}

// ---------------------------------------------------------------------------
// bf16 GEMM core: C[bmBM..][bnBN..] = A * B^T + bias, K = 1024.
// MODE 0: bf16 C (scaled). MODE 1: f32 C. MODE 2: write C^T into vT global
//   (vT[b*1024 + col][s], s = row % 2048) via LDS-bounce transpose.
// 4 waves (2x2). global_load_lds staging, pre-swizzled source columns.
// ---------------------------------------------------------------------------
template <int BM, int BN, int MODE>
__device__ __forceinline__ void gemm_core(unsigned short* smem,
                                          const unsigned short* __restrict__ A,
                                          const unsigned short* __restrict__ B,
                                          const float* __restrict__ bias,
                                          float scale, float* __restrict__ Cf,
                                          unsigned short* __restrict__ Cb) {
  unsigned short* As = smem;
  unsigned short* Bs = smem + BM * 64;
  const int tid = threadIdx.x;
  const int lane = tid & 63, w = tid >> 6;
  const int wm = w >> 1, wn = w & 1;
  const int l15 = lane & 15, l4 = lane >> 4;
  const int bm = blockIdx.y, bn = blockIdx.x;
  const int MF = BM / 32, NF = BN / 32;

  f32x4 acc[MF][NF];
#pragma unroll
  for (int m = 0; m < MF; ++m)
#pragma unroll
    for (int n = 0; n < NF; ++n) acc[m][n] = (f32x4){0.f, 0.f, 0.f, 0.f};

  for (int k0 = 0; k0 < D_MODEL; k0 += 64) {
    __syncthreads();
#pragma unroll
    for (int i = 0; i < BM / 32; ++i) {
      const int flat = i * 256 + tid;
      const int row = flat >> 3, g = flat & 7;
      gload16(&As[flat * 8], &A[(size_t)(bm * BM + row) * D_MODEL + k0 + ((g ^ (row & 7)) << 3)]);
    }
#pragma unroll
    for (int i = 0; i < BN / 32; ++i) {
      const int flat = i * 256 + tid;
      const int row = flat >> 3, g = flat & 7;
      gload16(&Bs[flat * 8], &B[(size_t)(bn * BN + row) * D_MODEL + k0 + ((g ^ (row & 7)) << 3)]);
    }
    __syncthreads();
#pragma unroll
    for (int kk = 0; kk < 2; ++kk) {
      bf16x8 af[MF], bf[NF];
#pragma unroll
      for (int m = 0; m < MF; ++m) {
        const int r = wm * (BM / 2) + m * 16 + l15;
        af[m] = *(const bf16x8*)&As[r * 64 + (((kk * 4 + l4) ^ (r & 7)) << 3)];
      }
#pragma unroll
      for (int n = 0; n < NF; ++n) {
        const int r = wn * (BN / 2) + n * 16 + l15;
        bf[n] = *(const bf16x8*)&Bs[r * 64 + (((kk * 4 + l4) ^ (r & 7)) << 3)];
      }
#pragma unroll
      for (int m = 0; m < MF; ++m)
#pragma unroll
        for (int n = 0; n < NF; ++n)
          acc[m][n] = __builtin_amdgcn_mfma_f32_16x16x32_bf16(af[m], bf[n], acc[m][n], 0, 0, 0);
    }
  }

  if (MODE != 2) {
#pragma unroll
    for (int m = 0; m < MF; ++m)
#pragma unroll
      for (int n = 0; n < NF; ++n) {
        const int col = bn * BN + wn * (BN / 2) + n * 16 + l15;
        const float bv = bias[col];
#pragma unroll
        for (int r = 0; r < 4; ++r) {
          const int row = bm * BM + wm * (BM / 2) + m * 16 + l4 * 4 + r;
          const float v = (acc[m][n][r] + bv) * scale;
          if (MODE == 0) Cb[(size_t)row * D_MODEL + col] = f2bf(v);
          else           Cf[(size_t)row * D_MODEL + col] = v;
        }
      }
  } else {
    // Transpose through LDS: T[cl][rl] (cl in [0,BN), rl in [0,BM)),
    // pitch BM*2 bytes, 16B-group swizzle g = (rl>>3) ^ (cl&7).
    unsigned short* T = smem;  // BN*BM*2 bytes <= As+Bs
    __syncthreads();
#pragma unroll
    for (int m = 0; m < MF; ++m)
#pragma unroll
      for (int n = 0; n < NF; ++n) {
        const int cl = wn * (BN / 2) + n * 16 + l15;
        const float bv = bias[bn * BN + cl];
#pragma unroll
        for (int r = 0; r < 4; ++r) {
          const int rl = wm * (BM / 2) + m * 16 + l4 * 4 + r;
          const int byte = cl * (BM * 2) + ((((rl >> 3) ^ (cl & 7))) << 4) + ((rl & 7) << 1);
          *(unsigned short*)((char*)T + byte) = f2bf(acc[m][n][r] + bv);
        }
      }
    __syncthreads();
    // read rows of T (b128) and store coalesced to vT[b*1024 + gcol][s]
#pragma unroll
    for (int c = 0; c < BN * BM / 8 / 256; ++c) {
      const int chunk = c * 256 + tid;
      const int cl = chunk >> 3, rl0 = (chunk & 7) * 8;
      const int byte = cl * (BM * 2) + (((rl0 >> 3) ^ (cl & 7)) << 4);
      const uint4 val = *(const uint4*)((const char*)T + byte);
      const int gcol = bn * BN + cl;
      const int bb = (bm * BM) >> 11;             // batch index
      const int s = ((bm * BM) & 2047) + rl0;     // seq pos
      *(uint4*)&Cb[(size_t)(bb * 1024 + gcol) * SS + s] = val;
    }
  }
}

__global__ __launch_bounds__(256) void gemm_qkv(
    const unsigned short* __restrict__ Xq, const unsigned short* __restrict__ Xk,
    const unsigned short* __restrict__ Xv,
    const unsigned short* __restrict__ Wq, const float* __restrict__ bq,
    const unsigned short* __restrict__ Wk, const float* __restrict__ bk,
    const unsigned short* __restrict__ Wv, const float* __restrict__ bv,
    unsigned short* __restrict__ q, unsigned short* __restrict__ k,
    unsigned short* __restrict__ vT) {
  __shared__ __align__(16) unsigned short smem[(64 + 128) * 64];
  const int z = blockIdx.z;
  if (z == 0) {
    gemm_core<64, 128, 0>(smem, Xq, Wq, bq, C1, nullptr, q);  // q pre-scaled
  } else if (z == 1) {
    gemm_core<64, 128, 0>(smem, Xk, Wk, bk, 1.0f, nullptr, k);
  } else {
    gemm_core<64, 128, 2>(smem, Xv, Wv, bv, 1.0f, nullptr, vT);
  }
}

__global__ __launch_bounds__(256) void gemm_o(const unsigned short* __restrict__ A,
                                              const unsigned short* __restrict__ W,
                                              const float* __restrict__ bi,
                                              float* __restrict__ out) {
  __shared__ __align__(16) unsigned short smem[(64 + 64) * 64];
  gemm_core<64, 64, 1>(smem, A, W, bi, 1.0f, out, nullptr);
}

// ---------------------------------------------------------------------------
// Flash attention, swapped-QK^T, in-register softmax. Block = (b,h,64 q-rows),
// 4 waves x 16 q-rows. K and V^T staged via global_load_lds (pre-swizzled src).
// q was pre-scaled by (1/8)*log2(e), so p = exp2(st - rm) directly.
// ---------------------------------------------------------------------------
__global__ __launch_bounds__(256) void attn_kernel(
    const unsigned short* __restrict__ Qp, const unsigned short* __restrict__ Kp,
    const unsigned short* __restrict__ vTp, unsigned short* __restrict__ Op) {
  __shared__ __align__(16) unsigned short Kt[64 * 64];
  __shared__ __align__(16) unsigned short Vt[64 * 64];     // [d][s]
  __shared__ __align__(16) unsigned short Pt[4][16 * 64];  // per-wave P
  const int tid = threadIdx.x;
  const int lane = tid & 63, w = tid >> 6;
  const int l15 = lane & 15, l4 = lane >> 4;
  const int bh = blockIdx.x;  // 0..31
  const int b = bh >> 4, h = bh & 15;
  const int qb = blockIdx.y;  // 0..31
  const size_t baseQ = (size_t)b * SS * D_MODEL + (size_t)h * DK;
  const size_t baseV = (size_t)(b * 1024 + h * 64) * SS;  // vT rows for this head

  const int qrow = qb * 64 + w * 16 + l15;
  bf16x8 aq[2];
#pragma unroll
  for (int kk = 0; kk < 2; ++kk)
    aq[kk] = *(const bf16x8*)&Qp[baseQ + (size_t)qrow * D_MODEL + kk * 32 + l4 * 8];

  float rm = -1e30f, rs = 0.f;
  f32x4 acc[4];
#pragma unroll
  for (int d = 0; d < 4; ++d) acc[d] = (f32x4){0.f, 0.f, 0.f, 0.f};

  for (int kt = 0; kt < SS / 64; ++kt) {
    __syncthreads();
#pragma unroll
    for (int i = 0; i < 2; ++i) {  // K tile: 64x64
      const int flat = (w * 2 + i) * 64 + lane;
      const int row = flat >> 3, g = flat & 7;
      gload16(&Kt[flat * 8], &Kp[baseQ + (size_t)(kt * 64 + row) * D_MODEL + ((g ^ (row & 7)) << 3)]);
    }
#pragma unroll
    for (int i = 0; i < 2; ++i) {  // V^T tile: rows d, cols s
      const int flat = (w * 2 + i) * 64 + lane;
      const int row = flat >> 3, g = flat & 7;
      gload16(&Vt[flat * 8], &vTp[baseV + (size_t)row * SS + kt * 64 + ((g ^ (row & 7)) << 3)]);
    }
    __syncthreads();

    // swapped QK^T: st[n] reg r holds key n*16+l4*4+r for q-row l15
    f32x4 st[4];
#pragma unroll
    for (int n = 0; n < 4; ++n) st[n] = (f32x4){0.f, 0.f, 0.f, 0.f};
#pragma unroll
    for (int kk = 0; kk < 2; ++kk) {
      bf16x8 kf[4];
#pragma unroll
      for (int n = 0; n < 4; ++n) {
        const int r = n * 16 + l15;
        kf[n] = *(const bf16x8*)&Kt[r * 64 + (((kk * 4 + l4) ^ (r & 7)) << 3)];
      }
#pragma unroll
      for (int n = 0; n < 4; ++n)
        st[n] = __builtin_amdgcn_mfma_f32_16x16x32_bf16(kf[n], aq[kk], st[n], 0, 0, 0);
    }

    // online softmax (q = l15; scores already in log2 units)
    float mx = st[0][0];
#pragma unroll
    for (int n = 0; n < 4; ++n)
#pragma unroll
      for (int r = 0; r < 4; ++r) mx = fmaxf(mx, st[n][r]);
    mx = fmaxf(mx, __shfl_xor(mx, 16));
    mx = fmaxf(mx, __shfl_xor(mx, 32));
    if (__any(mx > rm)) {
      const float nm = fmaxf(rm, mx);
      const float alpha = exp2f(rm - nm);
      rm = nm;
      rs *= alpha;
#pragma unroll
      for (int r = 0; r < 4; ++r) {
        const float ar = __shfl(alpha, l4 * 4 + r);
#pragma unroll
        for (int d = 0; d < 4; ++d) acc[d][r] *= ar;
      }
    }
    float ps = 0.f;
#pragma unroll
    for (int n = 0; n < 4; ++n)
#pragma unroll
      for (int r = 0; r < 4; ++r) {
        const float p = exp2f(st[n][r] - rm);
        st[n][r] = p;
        ps += p;
      }
    ps += __shfl_xor(ps, 16);
    ps += __shfl_xor(ps, 32);
    rs += ps;

    // P -> per-wave LDS (v_cvt_pk_bf16_f32 pairs, swizzled u32 writes)
#pragma unroll
    for (int n = 0; n < 4; ++n)
#pragma unroll
      for (int c = 0; c < 2; ++c) {
        const int col = n * 16 + l4 * 4 + 2 * c;
        const int sw = (((col >> 3) ^ (l15 & 7)) << 3) + (col & 7);
        *(unsigned*)&Pt[w][l15 * 64 + sw] = cvtpk(st[n][2 * c], st[n][2 * c + 1]);
      }

    // PV
#pragma unroll
    for (int kk = 0; kk < 2; ++kk) {
      const bf16x8 ap = *(const bf16x8*)&Pt[w][l15 * 64 + (((kk * 4 + l4) ^ (l15 & 7)) << 3)];
      bf16x8 vf[4];
#pragma unroll
      for (int d = 0; d < 4; ++d) {
        const int r = d * 16 + l15;
        vf[d] = *(const bf16x8*)&Vt[r * 64 + (((kk * 4 + l4) ^ (r & 7)) << 3)];
      }
#pragma unroll
      for (int d = 0; d < 4; ++d)
        acc[d] = __builtin_amdgcn_mfma_f32_16x16x32_bf16(ap, vf[d], acc[d], 0, 0, 0);
    }
  }

  float rsb[4];
#pragma unroll
  for (int r = 0; r < 4; ++r) rsb[r] = __shfl(rs, l4 * 4 + r);
#pragma unroll
  for (int d = 0; d < 4; ++d)
#pragma unroll
    for (int r = 0; r < 4; ++r) {
      const int orow = qb * 64 + w * 16 + l4 * 4 + r;
      Op[baseQ + (size_t)orow * D_MODEL + d * 16 + l15] = f2bf(acc[d][r] / rsb[r]);
    }
}

extern "C" void kernel_launch(void* const* d_in, const int* in_sizes, int n_in,
                              void* d_out, int out_size, void* d_ws, size_t ws_size,
                              hipStream_t stream) {
  const float* Qin = (const float*)d_in[0];
  const float* Kin = (const float*)d_in[1];
  const float* Vin = (const float*)d_in[2];
  const float* Wq = (const float*)d_in[3];
  const float* bq = (const float*)d_in[4];
  const float* Wk = (const float*)d_in[5];
  const float* bk = (const float*)d_in[6];
  const float* Wv = (const float*)d_in[7];
  const float* bv = (const float*)d_in[8];
  const float* Wo = (const float*)d_in[9];
  const float* bo = (const float*)d_in[10];
  float* out = (float*)d_out;

  const size_t NX = (size_t)MROWS * D_MODEL;
  const size_t NW = (size_t)D_MODEL * D_MODEL;
  unsigned short* ws = (unsigned short*)d_ws;
  unsigned short* q  = ws;            // projected q (bf16, pre-scaled)
  unsigned short* k  = ws + NX;       // projected k
  unsigned short* vT = ws + 2 * NX;   // projected v, transposed [b*1024+col][s]
  unsigned short* Xq = ws + 3 * NX;   // bf16 inputs (Xq reused as ao)
  unsigned short* Xk = ws + 4 * NX;
  unsigned short* Xv = ws + 5 * NX;
  unsigned short* wq = ws + 6 * NX;
  unsigned short* wk = wq + NW;
  unsigned short* wv = wk + NW;
  unsigned short* wo = wv + NW;
  unsigned short* ao = Xq;

  CvtArgs ca;
  ca.s[0] = Qin; ca.d[0] = Xq; ca.n8[0] = (int)(NX / 8);
  ca.s[1] = Kin; ca.d[1] = Xk; ca.n8[1] = (int)(NX / 8);
  ca.s[2] = Vin; ca.d[2] = Xv; ca.n8[2] = (int)(NX / 8);
  ca.s[3] = Wq;  ca.d[3] = wq; ca.n8[3] = (int)(NW / 8);
  ca.s[4] = Wk;  ca.d[4] = wk; ca.n8[4] = (int)(NW / 8);
  ca.s[5] = Wv;  ca.d[5] = wv; ca.n8[5] = (int)(NW / 8);
  ca.s[6] = Wo;  ca.d[6] = wo; ca.n8[6] = (int)(NW / 8);
  convert_bf16<<<dim3(1024, 7), 256, 0, stream>>>(ca);

  gemm_qkv<<<dim3(D_MODEL / 128, MROWS / 64, 3), 256, 0, stream>>>(
      Xq, Xk, Xv, wq, bq, wk, bk, wv, bv, q, k, vT);
  attn_kernel<<<dim3(BB * NHEAD, SS / 64), 256, 0, stream>>>(q, k, vT, ao);
  gemm_o<<<dim3(D_MODEL / 64, MROWS / 64), 256, 0, stream>>>(ao, wo, bo, out);
}

// Round 4
// 237.167 us; speedup vs baseline: 1.5351x; 1.0643x over previous
//
#include <hip/hip_runtime.h>

// ---------------------------------------------------------------------------
// MHA: out = (softmax(split(XqWq^T+bq) @ split(XkWk^T+bk)^T / 8) @ split(XvWv^T+bv)) @ Wo^T + bo
// B=2, S=2048, D=1024, H=16, Dk=64. fp32 I/O; bf16 MFMA compute.
// R4: 2-phase double-buffered GEMMs (stage-next || compute-cur, 1 barrier/step);
//     attn: dbuf K/V, ones-column MFMA row-sum, v_max3 tree, defer-max THR=8.
// ---------------------------------------------------------------------------

typedef short bf16x8 __attribute__((ext_vector_type(8)));
typedef float f32x4 __attribute__((ext_vector_type(4)));

#define D_MODEL 1024
#define NHEAD 16
#define DK 64
#define BB 2
#define SS 2048
#define MROWS (BB * SS) /* 4096 */
#define C1 0.18033688011112042f /* (1/8)*log2(e) */

__device__ __forceinline__ unsigned short f2bf(float f) {
  unsigned u = __builtin_bit_cast(unsigned, f);
  u += 0x7fffu + ((u >> 16) & 1u);  // RNE
  return (unsigned short)(u >> 16);
}
__device__ __forceinline__ unsigned pack2(float a, float b) {
  return (unsigned)f2bf(a) | ((unsigned)f2bf(b) << 16);
}
__device__ __forceinline__ unsigned cvtpk(float lo, float hi) {
  unsigned r;
  asm("v_cvt_pk_bf16_f32 %0, %1, %2" : "=v"(r) : "v"(lo), "v"(hi));
  return r;
}
__device__ __forceinline__ float max3f(float a, float b, float c) {
  float d;
  asm("v_max3_f32 %0, %1, %2, %3" : "=v"(d) : "v"(a), "v"(b), "v"(c));
  return d;
}

typedef __attribute__((address_space(3))) unsigned int as3u;
typedef const __attribute__((address_space(1))) unsigned int as1u;
__device__ __forceinline__ void gload16(void* lds, const void* g) {
  __builtin_amdgcn_global_load_lds((as1u*)g, (as3u*)lds, 16, 0, 0);
}

// ---------------------------------------------------------------------------
// fp32 -> bf16 conversion pass
// ---------------------------------------------------------------------------
struct CvtArgs {
  const float* s[7];
  unsigned short* d[7];
  int n8[7];
};

__global__ __launch_bounds__(256) void convert_bf16(CvtArgs a) {
  const int slot = blockIdx.y;
  const float* __restrict__ s = a.s[slot];
  unsigned short* __restrict__ d = a.d[slot];
  const int n8 = a.n8[slot];
  for (int i = blockIdx.x * 256 + threadIdx.x; i < n8; i += gridDim.x * 256) {
    const size_t off = (size_t)i * 8;
    const float4 v0 = *(const float4*)&s[off];
    const float4 v1 = *(const float4*)&s[off + 4];
    uint4 p;
    p.x = pack2(v0.x, v0.y); p.y = pack2(v0.z, v0.w);
    p.z = pack2(v1.x, v1.y); p.w = pack2(v1.z, v1.w);
    *(uint4*)&d[off] = p;
  }
}

// ---------------------------------------------------------------------------
// bf16 GEMM core, 2-phase double-buffered. C = A * B^T + bias, K = 1024.
// MODE 0: bf16 C (scaled). MODE 1: f32 C. MODE 2: C^T -> vT[b*1024+col][s].
// 4 waves (2x2). global_load_lds staging with pre-swizzled source columns;
// per K-step: stage(next buf) -> ds_read+MFMA(cur buf) -> __syncthreads().
// ---------------------------------------------------------------------------
template <int BM, int BN, int MODE>
__device__ __forceinline__ void gemm_core(unsigned short* smem,
                                          const unsigned short* __restrict__ A,
                                          const unsigned short* __restrict__ B,
                                          const float* __restrict__ bias,
                                          float scale, float* __restrict__ Cf,
                                          unsigned short* __restrict__ Cb) {
  const int LDSZ = (BM + BN) * 64;  // elements per buffer
  const int tid = threadIdx.x;
  const int lane = tid & 63, w = tid >> 6;
  const int wm = w >> 1, wn = w & 1;
  const int l15 = lane & 15, l4 = lane >> 4;
  const int bm = blockIdx.y, bn = blockIdx.x;
  const int MF = BM / 32, NF = BN / 32;

  auto stage = [&](unsigned short* dst, int k0) {
    unsigned short* Asb = dst;
    unsigned short* Bsb = dst + BM * 64;
#pragma unroll
    for (int i = 0; i < BM / 32; ++i) {
      const int flat = i * 256 + tid;
      const int row = flat >> 3, g = flat & 7;
      gload16(&Asb[flat * 8], &A[(size_t)(bm * BM + row) * D_MODEL + k0 + ((g ^ (row & 7)) << 3)]);
    }
#pragma unroll
    for (int i = 0; i < BN / 32; ++i) {
      const int flat = i * 256 + tid;
      const int row = flat >> 3, g = flat & 7;
      gload16(&Bsb[flat * 8], &B[(size_t)(bn * BN + row) * D_MODEL + k0 + ((g ^ (row & 7)) << 3)]);
    }
  };

  f32x4 acc[MF][NF];
#pragma unroll
  for (int m = 0; m < MF; ++m)
#pragma unroll
    for (int n = 0; n < NF; ++n) acc[m][n] = (f32x4){0.f, 0.f, 0.f, 0.f};

  stage(smem, 0);
  __syncthreads();
  int cur = 0;
  for (int k0 = 0; k0 < D_MODEL; k0 += 64) {
    if (k0 + 64 < D_MODEL) stage(smem + (cur ^ 1) * LDSZ, k0 + 64);
    unsigned short* As = smem + cur * LDSZ;
    unsigned short* Bs = As + BM * 64;
#pragma unroll
    for (int kk = 0; kk < 2; ++kk) {
      bf16x8 af[MF], bf[NF];
#pragma unroll
      for (int m = 0; m < MF; ++m) {
        const int r = wm * (BM / 2) + m * 16 + l15;
        af[m] = *(const bf16x8*)&As[r * 64 + (((kk * 4 + l4) ^ (r & 7)) << 3)];
      }
#pragma unroll
      for (int n = 0; n < NF; ++n) {
        const int r = wn * (BN / 2) + n * 16 + l15;
        bf[n] = *(const bf16x8*)&Bs[r * 64 + (((kk * 4 + l4) ^ (r & 7)) << 3)];
      }
#pragma unroll
      for (int m = 0; m < MF; ++m)
#pragma unroll
        for (int n = 0; n < NF; ++n)
          acc[m][n] = __builtin_amdgcn_mfma_f32_16x16x32_bf16(af[m], bf[n], acc[m][n], 0, 0, 0);
    }
    __syncthreads();
    cur ^= 1;
  }

  if (MODE != 2) {
#pragma unroll
    for (int m = 0; m < MF; ++m)
#pragma unroll
      for (int n = 0; n < NF; ++n) {
        const int col = bn * BN + wn * (BN / 2) + n * 16 + l15;
        const float bv = bias[col];
#pragma unroll
        for (int r = 0; r < 4; ++r) {
          const int row = bm * BM + wm * (BM / 2) + m * 16 + l4 * 4 + r;
          const float v = (acc[m][n][r] + bv) * scale;
          if (MODE == 0) Cb[(size_t)row * D_MODEL + col] = f2bf(v);
          else           Cf[(size_t)row * D_MODEL + col] = v;
        }
      }
  } else {
    // Transpose through LDS: T[cl][rl], pitch BM*2 B, group swizzle (rl>>3)^(cl&7)
    unsigned short* T = smem;
#pragma unroll
    for (int m = 0; m < MF; ++m)
#pragma unroll
      for (int n = 0; n < NF; ++n) {
        const int cl = wn * (BN / 2) + n * 16 + l15;
        const float bv = bias[bn * BN + cl];
#pragma unroll
        for (int r = 0; r < 4; ++r) {
          const int rl = wm * (BM / 2) + m * 16 + l4 * 4 + r;
          const int byte = cl * (BM * 2) + ((((rl >> 3) ^ (cl & 7))) << 4) + ((rl & 7) << 1);
          *(unsigned short*)((char*)T + byte) = f2bf(acc[m][n][r] + bv);
        }
      }
    __syncthreads();
#pragma unroll
    for (int c = 0; c < BN * BM / 8 / 256; ++c) {
      const int chunk = c * 256 + tid;
      const int cl = chunk >> 3, rl0 = (chunk & 7) * 8;
      const int byte = cl * (BM * 2) + (((rl0 >> 3) ^ (cl & 7)) << 4);
      const uint4 val = *(const uint4*)((const char*)T + byte);
      const int gcol = bn * BN + cl;
      const int bb = (bm * BM) >> 11;
      const int s = ((bm * BM) & 2047) + rl0;
      *(uint4*)&Cb[(size_t)(bb * 1024 + gcol) * SS + s] = val;
    }
  }
}

__global__ __launch_bounds__(256, 3) void gemm_qkv(
    const unsigned short* __restrict__ Xq, const unsigned short* __restrict__ Xk,
    const unsigned short* __restrict__ Xv,
    const unsigned short* __restrict__ Wq, const float* __restrict__ bq,
    const unsigned short* __restrict__ Wk, const float* __restrict__ bk,
    const unsigned short* __restrict__ Wv, const float* __restrict__ bv,
    unsigned short* __restrict__ q, unsigned short* __restrict__ k,
    unsigned short* __restrict__ vT) {
  __shared__ __align__(16) unsigned short smem[2 * (64 + 128) * 64];  // 48 KB
  const int z = blockIdx.z;
  if (z == 0) {
    gemm_core<64, 128, 0>(smem, Xq, Wq, bq, C1, nullptr, q);  // q pre-scaled
  } else if (z == 1) {
    gemm_core<64, 128, 0>(smem, Xk, Wk, bk, 1.0f, nullptr, k);
  } else {
    gemm_core<64, 128, 2>(smem, Xv, Wv, bv, 1.0f, nullptr, vT);
  }
}

__global__ __launch_bounds__(256, 3) void gemm_o(const unsigned short* __restrict__ A,
                                                 const unsigned short* __restrict__ W,
                                                 const float* __restrict__ bi,
                                                 float* __restrict__ out) {
  __shared__ __align__(16) unsigned short smem[2 * (64 + 128) * 64];  // 48 KB
  gemm_core<64, 128, 1>(smem, A, W, bi, 1.0f, out, nullptr);
}

// ---------------------------------------------------------------------------
// Flash attention, swapped-QK^T, in-register softmax, dbuf K/V staging,
// row-sum by ones-column MFMA, defer-max THR=8 (scores are in log2 units).
// Block = (b,h,64 q-rows), 4 waves x 16 q-rows.
// ---------------------------------------------------------------------------
__global__ __launch_bounds__(256, 4) void attn_kernel(
    const unsigned short* __restrict__ Qp, const unsigned short* __restrict__ Kp,
    const unsigned short* __restrict__ vTp, unsigned short* __restrict__ Op) {
  __shared__ __align__(16) unsigned short Kt[2][64 * 64];
  __shared__ __align__(16) unsigned short Vt[2][64 * 64];  // [d][s]
  __shared__ __align__(16) unsigned short Pt[4][16 * 64];  // per-wave P
  const int tid = threadIdx.x;
  const int lane = tid & 63, w = tid >> 6;
  const int l15 = lane & 15, l4 = lane >> 4;
  const int bh = blockIdx.x;  // 0..31
  const int b = bh >> 4, h = bh & 15;
  const int qb = blockIdx.y;  // 0..31
  const size_t baseQ = (size_t)b * SS * D_MODEL + (size_t)h * DK;
  const size_t baseV = (size_t)(b * 1024 + h * 64) * SS;

  const int qrow = qb * 64 + w * 16 + l15;
  bf16x8 aq[2];
#pragma unroll
  for (int kk = 0; kk < 2; ++kk)
    aq[kk] = *(const bf16x8*)&Qp[baseQ + (size_t)qrow * D_MODEL + kk * 32 + l4 * 8];

  const bf16x8 vone = {0x3F80, 0x3F80, 0x3F80, 0x3F80, 0x3F80, 0x3F80, 0x3F80, 0x3F80};

  float rm = -1e30f;
  f32x4 acc[5];  // [0..3] = O dims, [4] = row-sum (denominator)
#pragma unroll
  for (int d = 0; d < 5; ++d) acc[d] = (f32x4){0.f, 0.f, 0.f, 0.f};

  auto stage = [&](int buf, int kt) {
#pragma unroll
    for (int i = 0; i < 2; ++i) {  // K tile 64x64
      const int flat = (w * 2 + i) * 64 + lane;
      const int row = flat >> 3, g = flat & 7;
      gload16(&Kt[buf][flat * 8],
              &Kp[baseQ + (size_t)(kt * 64 + row) * D_MODEL + ((g ^ (row & 7)) << 3)]);
    }
#pragma unroll
    for (int i = 0; i < 2; ++i) {  // V^T tile: rows d, cols s
      const int flat = (w * 2 + i) * 64 + lane;
      const int row = flat >> 3, g = flat & 7;
      gload16(&Vt[buf][flat * 8],
              &vTp[baseV + (size_t)row * SS + kt * 64 + ((g ^ (row & 7)) << 3)]);
    }
  };

  stage(0, 0);
  __syncthreads();
  int cur = 0;
  for (int kt = 0; kt < SS / 64; ++kt) {
    if (kt + 1 < SS / 64) stage(cur ^ 1, kt + 1);

    // swapped QK^T: st[n] reg r holds key n*16+l4*4+r for q-row l15
    f32x4 st[4];
#pragma unroll
    for (int n = 0; n < 4; ++n) st[n] = (f32x4){0.f, 0.f, 0.f, 0.f};
#pragma unroll
    for (int kk = 0; kk < 2; ++kk) {
      bf16x8 kf[4];
#pragma unroll
      for (int n = 0; n < 4; ++n) {
        const int r = n * 16 + l15;
        kf[n] = *(const bf16x8*)&Kt[cur][r * 64 + (((kk * 4 + l4) ^ (r & 7)) << 3)];
      }
#pragma unroll
      for (int n = 0; n < 4; ++n)
        st[n] = __builtin_amdgcn_mfma_f32_16x16x32_bf16(kf[n], aq[kk], st[n], 0, 0, 0);
    }

    // row max via v_max3 tree (16 values -> 8 ops), then cross-l4 reduce
    const float a0 = max3f(st[0][0], st[0][1], st[0][2]);
    const float a1 = max3f(st[0][3], st[1][0], st[1][1]);
    const float a2 = max3f(st[1][2], st[1][3], st[2][0]);
    const float a3 = max3f(st[2][1], st[2][2], st[2][3]);
    const float a4 = max3f(st[3][0], st[3][1], st[3][2]);
    float mx = fmaxf(max3f(a0, a1, a2), max3f(a3, a4, st[3][3]));
    mx = fmaxf(mx, __shfl_xor(mx, 16));
    mx = fmaxf(mx, __shfl_xor(mx, 32));
    // defer-max: only rescale when max grows by > 8 (log2 units; P <= 256)
    if (__any(mx > rm + 8.f)) {
      const float nm = fmaxf(rm, mx);
      const float alpha = exp2f(rm - nm);
      rm = nm;
#pragma unroll
      for (int r = 0; r < 4; ++r) {
        const float ar = __shfl(alpha, l4 * 4 + r);
#pragma unroll
        for (int d = 0; d < 5; ++d) acc[d][r] *= ar;
      }
    }
#pragma unroll
    for (int n = 0; n < 4; ++n)
#pragma unroll
      for (int r = 0; r < 4; ++r) st[n][r] = exp2f(st[n][r] - rm);

    // P -> per-wave LDS (cvt_pk pairs, swizzled u32 writes; same-wave only)
#pragma unroll
    for (int n = 0; n < 4; ++n)
#pragma unroll
      for (int c = 0; c < 2; ++c) {
        const int col = n * 16 + l4 * 4 + 2 * c;
        const int sw = (((col >> 3) ^ (l15 & 7)) << 3) + (col & 7);
        *(unsigned*)&Pt[w][l15 * 64 + sw] = cvtpk(st[n][2 * c], st[n][2 * c + 1]);
      }

    // PV + ones-column row-sum
#pragma unroll
    for (int kk = 0; kk < 2; ++kk) {
      const bf16x8 ap = *(const bf16x8*)&Pt[w][l15 * 64 + (((kk * 4 + l4) ^ (l15 & 7)) << 3)];
      bf16x8 vf[4];
#pragma unroll
      for (int d = 0; d < 4; ++d) {
        const int r = d * 16 + l15;
        vf[d] = *(const bf16x8*)&Vt[cur][r * 64 + (((kk * 4 + l4) ^ (r & 7)) << 3)];
      }
#pragma unroll
      for (int d = 0; d < 4; ++d)
        acc[d] = __builtin_amdgcn_mfma_f32_16x16x32_bf16(ap, vf[d], acc[d], 0, 0, 0);
      acc[4] = __builtin_amdgcn_mfma_f32_16x16x32_bf16(ap, vone, acc[4], 0, 0, 0);
    }

    __syncthreads();
    cur ^= 1;
  }

  // epilogue: rows of acc are q = l4*4+r; acc[4][r] = denominator (replicated)
  float inv[4];
#pragma unroll
  for (int r = 0; r < 4; ++r) inv[r] = 1.0f / acc[4][r];
#pragma unroll
  for (int d = 0; d < 4; ++d)
#pragma unroll
    for (int r = 0; r < 4; ++r) {
      const int orow = qb * 64 + w * 16 + l4 * 4 + r;
      Op[baseQ + (size_t)orow * D_MODEL + d * 16 + l15] = f2bf(acc[d][r] * inv[r]);
    }
}

extern "C" void kernel_launch(void* const* d_in, const int* in_sizes, int n_in,
                              void* d_out, int out_size, void* d_ws, size_t ws_size,
                              hipStream_t stream) {
  const float* Qin = (const float*)d_in[0];
  const float* Kin = (const float*)d_in[1];
  const float* Vin = (const float*)d_in[2];
  const float* Wq = (const float*)d_in[3];
  const float* bq = (const float*)d_in[4];
  const float* Wk = (const float*)d_in[5];
  const float* bk = (const float*)d_in[6];
  const float* Wv = (const float*)d_in[7];
  const float* bv = (const float*)d_in[8];
  const float* Wo = (const float*)d_in[9];
  const float* bo = (const float*)d_in[10];
  float* out = (float*)d_out;

  const size_t NX = (size_t)MROWS * D_MODEL;
  const size_t NW = (size_t)D_MODEL * D_MODEL;
  unsigned short* ws = (unsigned short*)d_ws;
  unsigned short* q  = ws;            // projected q (bf16, pre-scaled by C1)
  unsigned short* k  = ws + NX;       // projected k
  unsigned short* vT = ws + 2 * NX;   // projected v^T [b*1024+col][s]
  unsigned short* Xq = ws + 3 * NX;   // bf16 inputs (Xq reused as ao)
  unsigned short* Xk = ws + 4 * NX;
  unsigned short* Xv = ws + 5 * NX;
  unsigned short* wq = ws + 6 * NX;
  unsigned short* wk = wq + NW;
  unsigned short* wv = wk + NW;
  unsigned short* wo = wv + NW;
  unsigned short* ao = Xq;

  CvtArgs ca;
  ca.s[0] = Qin; ca.d[0] = Xq; ca.n8[0] = (int)(NX / 8);
  ca.s[1] = Kin; ca.d[1] = Xk; ca.n8[1] = (int)(NX / 8);
  ca.s[2] = Vin; ca.d[2] = Xv; ca.n8[2] = (int)(NX / 8);
  ca.s[3] = Wq;  ca.d[3] = wq; ca.n8[3] = (int)(NW / 8);
  ca.s[4] = Wk;  ca.d[4] = wk; ca.n8[4] = (int)(NW / 8);
  ca.s[5] = Wv;  ca.d[5] = wv; ca.n8[5] = (int)(NW / 8);
  ca.s[6] = Wo;  ca.d[6] = wo; ca.n8[6] = (int)(NW / 8);
  convert_bf16<<<dim3(1024, 7), 256, 0, stream>>>(ca);

  gemm_qkv<<<dim3(D_MODEL / 128, MROWS / 64, 3), 256, 0, stream>>>(
      Xq, Xk, Xv, wq, bq, wk, bk, wv, bv, q, k, vT);
  attn_kernel<<<dim3(BB * NHEAD, SS / 64), 256, 0, stream>>>(q, k, vT, ao);
  gemm_o<<<dim3(D_MODEL / 128, MROWS / 64), 256, 0, stream>>>(ao, wo, bo, out);
}